// Round 1
// baseline (469.375 us; speedup 1.0000x reference)
//
#include <hip/hip_runtime.h>

#define D_NODE  128
#define N_BASIS 9
#define D_EDGE  128

__device__ __forceinline__ float fast_sigmoid(float x) {
    // |err| ~1e-6 relative — far under the 0.4 absmax threshold
    return __builtin_amdgcn_rcpf(1.0f + __expf(-x));
}

// Kernel A: atoms[a][b] = sigmoid(node_feat[a,:] @ W_atom[:,b] + b_atom[b])
__global__ __launch_bounds__(256) void atoms_kernel(
    const float* __restrict__ node_feat,
    const float* __restrict__ W_atom,
    const float* __restrict__ b_atom,
    float* __restrict__ atoms, int n_atoms)
{
    __shared__ float sW[D_NODE * N_BASIS];
    for (int t = threadIdx.x; t < D_NODE * N_BASIS; t += 256)
        sW[t] = W_atom[t];
    __syncthreads();
    int idx = blockIdx.x * 256 + threadIdx.x;
    int total = n_atoms * N_BASIS;
    if (idx >= total) return;
    int a = idx / N_BASIS;
    int b = idx - a * N_BASIS;
    const float* row = node_feat + a * D_NODE;
    float acc = b_atom[b];
#pragma unroll 8
    for (int i = 0; i < D_NODE; ++i)
        acc += row[i] * sW[i * N_BASIS + b];
    atoms[idx] = fast_sigmoid(acc);
}

// Kernel B: CSR row_ptr from sorted segment_ids (covers empty segments + tail).
__global__ __launch_bounds__(256) void rowptr_kernel(
    const int* __restrict__ seg, int* __restrict__ row_ptr,
    int n_triples, int n_edges)
{
    int i = blockIdx.x * 256 + threadIdx.x;
    if (i >= n_triples) return;
    int cur  = seg[i];
    int prev = (i == 0) ? -1 : seg[i - 1];
    for (int s = prev + 1; s <= cur; ++s) row_ptr[s] = i;
    if (i == n_triples - 1) {
        for (int s = cur + 1; s <= n_edges; ++s) row_ptr[s] = n_triples;
    }
}

// Kernel C: fused triple-gather + segment-sum + gated MLP + residual.
// One wave (64 lanes) per edge; 4 waves per block.
__global__ __launch_bounds__(256) void edge_kernel(
    const float* __restrict__ edge_feat,
    const float* __restrict__ three_basis,
    const float* __restrict__ atoms,
    const int*   __restrict__ graph_dst,
    const int*   __restrict__ lg_dst,
    const int*   __restrict__ row_ptr,
    const float* __restrict__ W_gate, const float* __restrict__ b_gate,
    const float* __restrict__ W_sig,  const float* __restrict__ b_sig,
    float* __restrict__ out, int n_edges)
{
    int wave = threadIdx.x >> 6;
    int lane = threadIdx.x & 63;
    int e = blockIdx.x * 4 + wave;
    if (e >= n_edges) return;

    int start = row_ptr[e];
    int end   = row_ptr[e + 1];

    float acc[N_BASIS];
#pragma unroll
    for (int k = 0; k < N_BASIS; ++k) acc[k] = 0.0f;

    // Phase 1: strided accumulation over this edge's contiguous triple range
    for (int t = start + lane; t < end; t += 64) {
        int atom = graph_dst[lg_dst[t]];
        const float* tb = three_basis + (size_t)t * N_BASIS;
        const float* at = atoms + atom * N_BASIS;
#pragma unroll
        for (int k = 0; k < N_BASIS; ++k)
            acc[k] += tb[k] * at[k];
    }

    // Butterfly reduce: every lane ends with the full segment sum nb[9]
#pragma unroll
    for (int off = 1; off < 64; off <<= 1) {
#pragma unroll
        for (int k = 0; k < N_BASIS; ++k)
            acc[k] += __shfl_xor(acc[k], off, 64);
    }

    // Phase 2: gated MLP 9 -> 128, two channels per lane, + residual
    const float* efr  = edge_feat + (size_t)e * D_EDGE;
    float*       outr = out       + (size_t)e * D_EDGE;
#pragma unroll
    for (int h = 0; h < 2; ++h) {
        int j = lane + h * 64;
        float g = b_gate[j];
        float s = b_sig[j];
#pragma unroll
        for (int k = 0; k < N_BASIS; ++k) {
            g += acc[k] * W_gate[k * D_EDGE + j];
            s += acc[k] * W_sig[k * D_EDGE + j];
        }
        float silu = g * fast_sigmoid(g);
        outr[j] = efr[j] + silu * fast_sigmoid(s);
    }
}

extern "C" void kernel_launch(void* const* d_in, const int* in_sizes, int n_in,
                              void* d_out, int out_size, void* d_ws, size_t ws_size,
                              hipStream_t stream) {
    const float* node_feat   = (const float*)d_in[0];
    const float* edge_feat   = (const float*)d_in[1];
    const float* three_basis = (const float*)d_in[2];
    // d_in[3] three_cutoff: dead code in reference
    const float* W_atom      = (const float*)d_in[4];
    const float* b_atom      = (const float*)d_in[5];
    const float* W_gate      = (const float*)d_in[6];
    const float* b_gate      = (const float*)d_in[7];
    const float* W_sig       = (const float*)d_in[8];
    const float* b_sig       = (const float*)d_in[9];
    const int*   graph_dst   = (const int*)d_in[10];
    // d_in[11] lg_src: dead code in reference
    const int*   lg_dst      = (const int*)d_in[12];
    const int*   seg         = (const int*)d_in[13];

    int n_atoms   = in_sizes[0] / D_NODE;
    int n_edges   = in_sizes[1] / D_EDGE;
    int n_triples = in_sizes[2] / N_BASIS;

    // Workspace layout: atoms [n_atoms*9 f32] | row_ptr [n_edges+1 i32]
    float* atoms = (float*)d_ws;
    size_t atoms_bytes = ((size_t)n_atoms * N_BASIS * sizeof(float) + 255) & ~(size_t)255;
    int* row_ptr = (int*)((char*)d_ws + atoms_bytes);

    float* out = (float*)d_out;

    atoms_kernel<<<(n_atoms * N_BASIS + 255) / 256, 256, 0, stream>>>(
        node_feat, W_atom, b_atom, atoms, n_atoms);

    rowptr_kernel<<<(n_triples + 255) / 256, 256, 0, stream>>>(
        seg, row_ptr, n_triples, n_edges);

    edge_kernel<<<(n_edges + 3) / 4, 256, 0, stream>>>(
        edge_feat, three_basis, atoms, graph_dst, lg_dst, row_ptr,
        W_gate, b_gate, W_sig, b_sig, out, n_edges);
}